// Round 2
// baseline (2370.312 us; speedup 1.0000x reference)
//
#include <hip/hip_runtime.h>
#include <math.h>

// Problem constants
#define Bx 4
#define Tt 8192
#define Nn (Bx * Tt)        // 32768 tokens
#define Dd 512
#define Ee 8
#define Kk 2
#define Ff 2048
#define Cc 5120             // ceil(1.25 * N / E)
#define NK (Nn * Kk)        // 65536 routing slots

#define BM 128
#define BN 128
#define BK 16

__device__ __forceinline__ float gelu_exact(float v) {
    return 0.5f * v * (1.0f + erff(v * 0.70710678118654752440f));
}

// ---------------------------------------------------------------------------
// Kernel 1: gating — logits, softmax, top-2, normalized weights.
// One wave (64 lanes) per token; 4 tokens per 256-thread block.
// ---------------------------------------------------------------------------
__global__ __launch_bounds__(256) void moe_gate_kernel(
    const float* __restrict__ x, const float* __restrict__ gate_w,
    int* __restrict__ flat_e, float* __restrict__ wArr) {
    __shared__ float gw[Ee * Dd];   // 16 KB
    int tid = threadIdx.x;
    for (int i = tid; i < 1024; i += 256)
        ((float4*)gw)[i] = ((const float4*)gate_w)[i];
    __syncthreads();

    int wave = tid >> 6, lane = tid & 63;
    int token = blockIdx.x * 4 + wave;

    const float4* xr = (const float4*)(x + (size_t)token * Dd);
    float4 xa = xr[lane];
    float4 xb = xr[lane + 64];

    float acc[Ee];
#pragma unroll
    for (int e = 0; e < Ee; e++) {
        const float4* g = (const float4*)(gw + e * Dd);
        float4 ga = g[lane], gb = g[lane + 64];
        acc[e] = xa.x * ga.x + xa.y * ga.y + xa.z * ga.z + xa.w * ga.w +
                 xb.x * gb.x + xb.y * gb.y + xb.z * gb.z + xb.w * gb.w;
    }
#pragma unroll
    for (int off = 32; off >= 1; off >>= 1) {
#pragma unroll
        for (int e = 0; e < Ee; e++) acc[e] += __shfl_xor(acc[e], off, 64);
    }

    if (lane == 0) {
        float m = acc[0];
#pragma unroll
        for (int e = 1; e < Ee; e++) m = fmaxf(m, acc[e]);
        float p[Ee], s = 0.f;
#pragma unroll
        for (int e = 0; e < Ee; e++) { p[e] = expf(acc[e] - m); s += p[e]; }
        // top-2 (ties -> lowest index, matching lax.top_k)
        int i0 = 0;
#pragma unroll
        for (int e = 1; e < Ee; e++) if (p[e] > p[i0]) i0 = e;
        int i1 = (i0 == 0) ? 1 : 0;
#pragma unroll
        for (int e = 0; e < Ee; e++) if (e != i0 && p[e] > p[i1]) i1 = e;
        float v0 = p[i0] / s, v1 = p[i1] / s;
        float inv = 1.f / (v0 + v1);
        flat_e[token * 2 + 0] = i0;
        flat_e[token * 2 + 1] = i1;
        wArr[token * 2 + 0] = v0 * inv;
        wArr[token * 2 + 1] = v1 * inv;
    }
}

// ---------------------------------------------------------------------------
// Kernel 2: per-block expert histogram (256 slots per block)
// ---------------------------------------------------------------------------
__global__ __launch_bounds__(256) void moe_hist_kernel(
    const int* __restrict__ flat_e, int* __restrict__ blockCounts) {
    __shared__ int cnt[Ee];
    int tid = threadIdx.x;
    if (tid < Ee) cnt[tid] = 0;
    __syncthreads();
    int e = flat_e[blockIdx.x * 256 + tid];
    atomicAdd(&cnt[e], 1);
    __syncthreads();
    if (tid < Ee) blockCounts[blockIdx.x * Ee + tid] = cnt[tid];
}

// ---------------------------------------------------------------------------
// Kernel 3: exclusive scan of block counts per expert (serial, tiny)
// ---------------------------------------------------------------------------
__global__ void moe_scan_kernel(const int* __restrict__ blockCounts,
                                int* __restrict__ blockOffsets,
                                int* __restrict__ counts) {
    int e = threadIdx.x;
    if (e >= Ee) return;
    int run = 0;
    for (int b = 0; b < 256; b++) {
        blockOffsets[b * Ee + e] = run;
        run += blockCounts[b * Ee + e];
    }
    counts[e] = min(run, Cc);
}

// ---------------------------------------------------------------------------
// Kernel 4: in-order position assignment + scatter routing records.
// Reproduces the reference cumsum order: slot index i = token*K + k.
// ---------------------------------------------------------------------------
__global__ __launch_bounds__(256) void moe_scatter_kernel(
    const int* __restrict__ flat_e, const float* __restrict__ wArr,
    const int* __restrict__ blockOffsets,
    int* __restrict__ srcOf, float* __restrict__ wSlot) {
    __shared__ int waveCnt[4][Ee];
    int tid = threadIdx.x;
    int i = blockIdx.x * 256 + tid;
    int e = flat_e[i];
    int wv = tid >> 6, lane = tid & 63;
    unsigned long long ltmask = (1ull << lane) - 1ull;
    int myrank = 0;
#pragma unroll
    for (int ee = 0; ee < Ee; ee++) {
        unsigned long long m = __ballot(e == ee);
        if (e == ee) myrank = __popcll(m & ltmask);
        if (lane == 0) waveCnt[wv][ee] = __popcll(m);
    }
    __syncthreads();
    int base = blockOffsets[blockIdx.x * Ee + e];
    for (int w = 0; w < wv; w++) base += waveCnt[w][e];
    int pos = base + myrank;
    if (pos < Cc) {
        srcOf[e * Cc + pos] = i >> 1;   // token id
        wSlot[e * Cc + pos] = wArr[i];
    }
}

// ---------------------------------------------------------------------------
// Kernel 5: GEMM1 (gathered A): h = gelu(x[src] @ w1[e] + b1[e])
// 128x128 tile, BK=16, 8x8 micro-tile, fp32. grid.z = experts in chunk.
// r0 = row offset into each expert's slot list (workspace row-chunking).
// ---------------------------------------------------------------------------
__global__ __launch_bounds__(256) void moe_gemm1_kernel(
    const float* __restrict__ x, const float* __restrict__ w1,
    const float* __restrict__ b1, const int* __restrict__ srcOf,
    const int* __restrict__ counts, int chunk0, int r0,
    float* __restrict__ hbuf) {
    int le = blockIdx.z;
    int e = chunk0 + le;
    int count = counts[e] - r0;          // rows of this expert in this chunk
    int m0 = blockIdx.y * BM;
    if (m0 >= count) return;
    int f0 = blockIdx.x * BN;
    int RC = gridDim.y * BM;             // rows per chunk (h stride block)

    const float* w1e = w1 + (size_t)e * Dd * Ff;
    const float* b1e = b1 + (size_t)e * Ff;
    const int* srcE = srcOf + (size_t)e * Cc + r0;
    float* h = hbuf + (size_t)le * RC * Ff;

    __shared__ float As[BK][BM + 4];
    __shared__ float Bs[BK][BN + 4];
    __shared__ int srcs[BM];

    int tid = threadIdx.x;
    if (tid < BM) {
        int m = m0 + tid;
        srcs[tid] = (m < count) ? srcE[m] : -1;
    }
    __syncthreads();

    int ty = tid >> 4, tx = tid & 15;
    int arow = tid >> 2, akq = tid & 3;     // A: rows arow, arow+64; k = akq*4..+3
    int bkk = tid >> 5, bfq = tid & 31;     // B: k-rows bkk, bkk+8; f = bfq*4..+3

    float acc[8][8];
#pragma unroll
    for (int i = 0; i < 8; i++)
#pragma unroll
        for (int j = 0; j < 8; j++) acc[i][j] = 0.f;

    for (int k0 = 0; k0 < Dd; k0 += BK) {
        int s0 = srcs[arow], s1 = srcs[arow + 64];
        float4 a0 = make_float4(0.f, 0.f, 0.f, 0.f), a1 = a0;
        if (s0 >= 0) a0 = *(const float4*)(x + (size_t)s0 * Dd + k0 + akq * 4);
        if (s1 >= 0) a1 = *(const float4*)(x + (size_t)s1 * Dd + k0 + akq * 4);
        float4 b0 = *(const float4*)(w1e + (size_t)(k0 + bkk) * Ff + f0 + bfq * 4);
        float4 b1v = *(const float4*)(w1e + (size_t)(k0 + bkk + 8) * Ff + f0 + bfq * 4);
        __syncthreads();
        As[akq * 4 + 0][arow] = a0.x; As[akq * 4 + 1][arow] = a0.y;
        As[akq * 4 + 2][arow] = a0.z; As[akq * 4 + 3][arow] = a0.w;
        As[akq * 4 + 0][arow + 64] = a1.x; As[akq * 4 + 1][arow + 64] = a1.y;
        As[akq * 4 + 2][arow + 64] = a1.z; As[akq * 4 + 3][arow + 64] = a1.w;
        *(float4*)&Bs[bkk][bfq * 4] = b0;
        *(float4*)&Bs[bkk + 8][bfq * 4] = b1v;
        __syncthreads();
#pragma unroll
        for (int kk = 0; kk < BK; kk++) {
            float a[8], b[8];
            *(float4*)&a[0] = *(const float4*)&As[kk][ty * 4];
            *(float4*)&a[4] = *(const float4*)&As[kk][ty * 4 + 64];
            *(float4*)&b[0] = *(const float4*)&Bs[kk][tx * 4];
            *(float4*)&b[4] = *(const float4*)&Bs[kk][tx * 4 + 64];
#pragma unroll
            for (int i = 0; i < 8; i++)
#pragma unroll
                for (int j = 0; j < 8; j++)
                    acc[i][j] = fmaf(a[i], b[j], acc[i][j]);
        }
    }

    float bias[8];
    *(float4*)&bias[0] = *(const float4*)(b1e + f0 + tx * 4);
    *(float4*)&bias[4] = *(const float4*)(b1e + f0 + tx * 4 + 64);
#pragma unroll
    for (int i = 0; i < 8; i++) {
        int m = m0 + ty * 4 + (i & 3) + ((i >> 2) << 6);
        float4 o0, o1;
        o0.x = gelu_exact(acc[i][0] + bias[0]);
        o0.y = gelu_exact(acc[i][1] + bias[1]);
        o0.z = gelu_exact(acc[i][2] + bias[2]);
        o0.w = gelu_exact(acc[i][3] + bias[3]);
        o1.x = gelu_exact(acc[i][4] + bias[4]);
        o1.y = gelu_exact(acc[i][5] + bias[5]);
        o1.z = gelu_exact(acc[i][6] + bias[6]);
        o1.w = gelu_exact(acc[i][7] + bias[7]);
        *(float4*)(h + (size_t)m * Ff + f0 + tx * 4) = o0;
        *(float4*)(h + (size_t)m * Ff + f0 + tx * 4 + 64) = o1;
    }
}

// ---------------------------------------------------------------------------
// Kernel 6: GEMM2 + weighted scatter: out[token] += w * (h @ w2[e] + b2[e])
// grid.z = experts in this chunk. atomicAdd handles cross-expert token overlap.
// ---------------------------------------------------------------------------
__global__ __launch_bounds__(256) void moe_gemm2_kernel(
    const float* __restrict__ hbuf, const float* __restrict__ w2,
    const float* __restrict__ b2, const int* __restrict__ srcOf,
    const float* __restrict__ wSlot, const int* __restrict__ counts,
    int chunk0, int r0, float* __restrict__ out) {
    int le = blockIdx.z;
    int e = chunk0 + le;
    int count = counts[e] - r0;
    int m0 = blockIdx.y * BM;
    if (m0 >= count) return;
    int d0 = blockIdx.x * BN;
    int RC = gridDim.y * BM;

    const float* h = hbuf + (size_t)le * RC * Ff;
    const float* w2e = w2 + (size_t)e * Ff * Dd;
    const float* b2e = b2 + (size_t)e * Dd;
    const int* srcE = srcOf + (size_t)e * Cc + r0;
    const float* wE = wSlot + (size_t)e * Cc + r0;

    __shared__ float As[BK][BM + 4];
    __shared__ float Bs[BK][BN + 4];

    int tid = threadIdx.x;
    int ty = tid >> 4, tx = tid & 15;
    int arow = tid >> 2, akq = tid & 3;
    int bkk = tid >> 5, bfq = tid & 31;

    float acc[8][8];
#pragma unroll
    for (int i = 0; i < 8; i++)
#pragma unroll
        for (int j = 0; j < 8; j++) acc[i][j] = 0.f;

    for (int k0 = 0; k0 < Ff; k0 += BK) {
        float4 a0 = *(const float4*)(h + (size_t)(m0 + arow) * Ff + k0 + akq * 4);
        float4 a1 = *(const float4*)(h + (size_t)(m0 + arow + 64) * Ff + k0 + akq * 4);
        float4 b0 = *(const float4*)(w2e + (size_t)(k0 + bkk) * Dd + d0 + bfq * 4);
        float4 b1v = *(const float4*)(w2e + (size_t)(k0 + bkk + 8) * Dd + d0 + bfq * 4);
        __syncthreads();
        As[akq * 4 + 0][arow] = a0.x; As[akq * 4 + 1][arow] = a0.y;
        As[akq * 4 + 2][arow] = a0.z; As[akq * 4 + 3][arow] = a0.w;
        As[akq * 4 + 0][arow + 64] = a1.x; As[akq * 4 + 1][arow + 64] = a1.y;
        As[akq * 4 + 2][arow + 64] = a1.z; As[akq * 4 + 3][arow + 64] = a1.w;
        *(float4*)&Bs[bkk][bfq * 4] = b0;
        *(float4*)&Bs[bkk + 8][bfq * 4] = b1v;
        __syncthreads();
#pragma unroll
        for (int kk = 0; kk < BK; kk++) {
            float a[8], b[8];
            *(float4*)&a[0] = *(const float4*)&As[kk][ty * 4];
            *(float4*)&a[4] = *(const float4*)&As[kk][ty * 4 + 64];
            *(float4*)&b[0] = *(const float4*)&Bs[kk][tx * 4];
            *(float4*)&b[4] = *(const float4*)&Bs[kk][tx * 4 + 64];
#pragma unroll
            for (int i = 0; i < 8; i++)
#pragma unroll
                for (int j = 0; j < 8; j++)
                    acc[i][j] = fmaf(a[i], b[j], acc[i][j]);
        }
    }

    float bias[8];
    *(float4*)&bias[0] = *(const float4*)(b2e + d0 + tx * 4);
    *(float4*)&bias[4] = *(const float4*)(b2e + d0 + tx * 4 + 64);
#pragma unroll
    for (int i = 0; i < 8; i++) {
        int m = m0 + ty * 4 + (i & 3) + ((i >> 2) << 6);
        if (m < count) {
            int token = srcE[m];
            float wgt = wE[m];
            float* op = out + (size_t)token * Dd + d0;
#pragma unroll
            for (int j = 0; j < 8; j++) {
                int col = tx * 4 + (j & 3) + ((j >> 2) << 6);
                atomicAdd(&op[col], wgt * (acc[i][j] + bias[j]));
            }
        }
    }
}

// ---------------------------------------------------------------------------
extern "C" void kernel_launch(void* const* d_in, const int* in_sizes, int n_in,
                              void* d_out, int out_size, void* d_ws, size_t ws_size,
                              hipStream_t stream) {
    const float* x      = (const float*)d_in[0];
    const float* gate_w = (const float*)d_in[1];
    const float* w1     = (const float*)d_in[2];
    const float* b1     = (const float*)d_in[3];
    const float* w2     = (const float*)d_in[4];
    const float* b2     = (const float*)d_in[5];
    float* out = (float*)d_out;

    char* p = (char*)d_ws;
    int*   flat_e       = (int*)p;    p += (size_t)NK * 4;
    float* wArr         = (float*)p;  p += (size_t)NK * 4;
    int*   blockCounts  = (int*)p;    p += 256 * Ee * 4;
    int*   blockOffsets = (int*)p;    p += 256 * Ee * 4;
    int*   counts       = (int*)p;    p += 64 * 4;
    int*   srcOf        = (int*)p;    p += (size_t)Ee * Cc * 4;
    float* wSlot        = (float*)p;  p += (size_t)Ee * Cc * 4;
    size_t off = ((size_t)(p - (char*)d_ws) + 255) & ~(size_t)255;
    float* hbuf = (float*)((char*)d_ws + off);
    size_t avail = (ws_size > off) ? ws_size - off : 0;

    // Fit the h buffer: first shrink experts-per-chunk P, then row-chunk RC.
    int P = Ee, RC = Cc;
    while (P > 1 && (size_t)P * RC * Ff * 4 > avail) P >>= 1;
    while (RC > BM && (size_t)RC * Ff * 4 > avail)
        RC = ((RC / 2 + BM - 1) / BM) * BM;

    moe_gate_kernel<<<Nn / 4, 256, 0, stream>>>(x, gate_w, flat_e, wArr);
    moe_hist_kernel<<<NK / 256, 256, 0, stream>>>(flat_e, blockCounts);
    moe_scan_kernel<<<1, 64, 0, stream>>>(blockCounts, blockOffsets, counts);
    moe_scatter_kernel<<<NK / 256, 256, 0, stream>>>(flat_e, wArr, blockOffsets,
                                                     srcOf, wSlot);
    hipMemsetAsync(d_out, 0, (size_t)Nn * Dd * sizeof(float), stream);

    for (int c0 = 0; c0 < Ee; c0 += P) {
        for (int r0 = 0; r0 < Cc; r0 += RC) {
            moe_gemm1_kernel<<<dim3(Ff / BN, RC / BM, P), 256, 0, stream>>>(
                x, w1, b1, srcOf, counts, c0, r0, hbuf);
            moe_gemm2_kernel<<<dim3(Dd / BN, RC / BM, P), 256, 0, stream>>>(
                hbuf, w2, b2, srcOf, wSlot, counts, c0, r0, out);
        }
    }
}

// Round 3
// 685.824 us; speedup vs baseline: 3.4562x; 3.4562x over previous
//
#include <hip/hip_runtime.h>
#include <math.h>

// Problem constants
#define Bx 4
#define Tt 8192
#define Nn (Bx * Tt)        // 32768 tokens
#define Dd 512
#define Ee 8
#define Kk 2
#define Ff 2048
#define Cc 5120             // ceil(1.25 * N / E)
#define NK (Nn * Kk)        // 65536 routing slots

typedef unsigned short ushort_t;
typedef __attribute__((ext_vector_type(8))) short bf16x8;   // MFMA A/B frag (4 VGPR)
typedef __attribute__((ext_vector_type(4))) float f32x4;    // MFMA C/D frag

__device__ __forceinline__ float gelu_exact(float v) {
    return 0.5f * v * (1.0f + erff(v * 0.70710678118654752440f));
}

// fp32 -> bf16 RNE
__device__ __forceinline__ ushort_t f2bf(float f) {
    union { float f; unsigned u; } v; v.f = f;
    unsigned r = v.u + 0x7fffu + ((v.u >> 16) & 1u);
    return (ushort_t)(r >> 16);
}

// async global->LDS, 16B per lane. LDS dest must be wave-uniform base; HW adds lane*16.
__device__ __forceinline__ void gload_lds16(const ushort_t* g, short* l) {
    __builtin_amdgcn_global_load_lds(
        (const __attribute__((address_space(1))) unsigned int*)g,
        (__attribute__((address_space(3))) unsigned int*)l, 16, 0, 0);
}

// ---------------------------------------------------------------------------
// Kernel 1: gating — logits, softmax, top-2, normalized weights (fp32, verified)
// ---------------------------------------------------------------------------
__global__ __launch_bounds__(256) void moe_gate_kernel(
    const float* __restrict__ x, const float* __restrict__ gate_w,
    int* __restrict__ flat_e, float* __restrict__ wArr) {
    __shared__ float gw[Ee * Dd];   // 16 KB
    int tid = threadIdx.x;
    for (int i = tid; i < 1024; i += 256)
        ((float4*)gw)[i] = ((const float4*)gate_w)[i];
    __syncthreads();

    int wave = tid >> 6, lane = tid & 63;
    int token = blockIdx.x * 4 + wave;

    const float4* xr = (const float4*)(x + (size_t)token * Dd);
    float4 xa = xr[lane];
    float4 xb = xr[lane + 64];

    float acc[Ee];
#pragma unroll
    for (int e = 0; e < Ee; e++) {
        const float4* g = (const float4*)(gw + e * Dd);
        float4 ga = g[lane], gb = g[lane + 64];
        acc[e] = xa.x * ga.x + xa.y * ga.y + xa.z * ga.z + xa.w * ga.w +
                 xb.x * gb.x + xb.y * gb.y + xb.z * gb.z + xb.w * gb.w;
    }
#pragma unroll
    for (int off = 32; off >= 1; off >>= 1) {
#pragma unroll
        for (int e = 0; e < Ee; e++) acc[e] += __shfl_xor(acc[e], off, 64);
    }

    if (lane == 0) {
        float m = acc[0];
#pragma unroll
        for (int e = 1; e < Ee; e++) m = fmaxf(m, acc[e]);
        float p[Ee], s = 0.f;
#pragma unroll
        for (int e = 0; e < Ee; e++) { p[e] = expf(acc[e] - m); s += p[e]; }
        int i0 = 0;
#pragma unroll
        for (int e = 1; e < Ee; e++) if (p[e] > p[i0]) i0 = e;
        int i1 = (i0 == 0) ? 1 : 0;
#pragma unroll
        for (int e = 0; e < Ee; e++) if (e != i0 && p[e] > p[i1]) i1 = e;
        float v0 = p[i0] / s, v1 = p[i1] / s;
        float inv = 1.f / (v0 + v1);
        flat_e[token * 2 + 0] = i0;
        flat_e[token * 2 + 1] = i1;
        wArr[token * 2 + 0] = v0 * inv;
        wArr[token * 2 + 1] = v1 * inv;
    }
}

// ---------------------------------------------------------------------------
// Kernels 2-4: routing (verified round 2): histogram -> scan -> ordered scatter
// ---------------------------------------------------------------------------
__global__ __launch_bounds__(256) void moe_hist_kernel(
    const int* __restrict__ flat_e, int* __restrict__ blockCounts) {
    __shared__ int cnt[Ee];
    int tid = threadIdx.x;
    if (tid < Ee) cnt[tid] = 0;
    __syncthreads();
    int e = flat_e[blockIdx.x * 256 + tid];
    atomicAdd(&cnt[e], 1);
    __syncthreads();
    if (tid < Ee) blockCounts[blockIdx.x * Ee + tid] = cnt[tid];
}

__global__ void moe_scan_kernel(const int* __restrict__ blockCounts,
                                int* __restrict__ blockOffsets,
                                int* __restrict__ counts) {
    int e = threadIdx.x;
    if (e >= Ee) return;
    int run = 0;
    for (int b = 0; b < 256; b++) {
        blockOffsets[b * Ee + e] = run;
        run += blockCounts[b * Ee + e];
    }
    counts[e] = min(run, Cc);
}

__global__ __launch_bounds__(256) void moe_scatter_kernel(
    const int* __restrict__ flat_e, const float* __restrict__ wArr,
    const int* __restrict__ blockOffsets,
    int* __restrict__ srcOf, float* __restrict__ wSlot) {
    __shared__ int waveCnt[4][Ee];
    int tid = threadIdx.x;
    int i = blockIdx.x * 256 + tid;
    int e = flat_e[i];
    int wv = tid >> 6, lane = tid & 63;
    unsigned long long ltmask = (1ull << lane) - 1ull;
    int myrank = 0;
#pragma unroll
    for (int ee = 0; ee < Ee; ee++) {
        unsigned long long m = __ballot(e == ee);
        if (e == ee) myrank = __popcll(m & ltmask);
        if (lane == 0) waveCnt[wv][ee] = __popcll(m);
    }
    __syncthreads();
    int base = blockOffsets[blockIdx.x * Ee + e];
    for (int w = 0; w < wv; w++) base += waveCnt[w][e];
    int pos = base + myrank;
    if (pos < Cc) {
        srcOf[e * Cc + pos] = i >> 1;   // token id
        wSlot[e * Cc + pos] = wArr[i];
    }
}

// ---------------------------------------------------------------------------
// Kernel 5: fp32 [E][R][Cn] -> bf16 [E][Cn][R] transpose (weights to B^T form)
// ---------------------------------------------------------------------------
__global__ __launch_bounds__(256) void moe_transpose_kernel(
    const float* __restrict__ in, ushort_t* __restrict__ out, int R, int Cn) {
    __shared__ float t[32][33];
    int ez = blockIdx.z;
    const float* ine = in + (size_t)ez * R * Cn;
    ushort_t* oute = out + (size_t)ez * R * Cn;
    int tx = threadIdx.x & 31, ty = threadIdx.x >> 5;   // 32 x 8
    int r0 = blockIdx.y * 32, c0 = blockIdx.x * 32;
#pragma unroll
    for (int j = 0; j < 4; j++)
        t[ty + j * 8][tx] = ine[(size_t)(r0 + ty + j * 8) * Cn + c0 + tx];
    __syncthreads();
#pragma unroll
    for (int j = 0; j < 4; j++)
        oute[(size_t)(c0 + ty + j * 8) * R + r0 + tx] = f2bf(t[tx][ty + j * 8]);
}

// ---------------------------------------------------------------------------
// Kernel 6: gather + fp32->bf16: xg[slot][d] = bf16(x[srcOf[slot]][d]) or 0
// One wave per slot row; 4 rows per block.
// ---------------------------------------------------------------------------
__global__ __launch_bounds__(256) void moe_gather_kernel(
    const float* __restrict__ x, const int* __restrict__ srcOf,
    const int* __restrict__ counts, int chunk0, ushort_t* __restrict__ xg) {
    int tid = threadIdx.x, wave = tid >> 6, lane = tid & 63;
    int sl = blockIdx.x * 4 + wave;      // local slot within chunk
    int le = sl / Cc, c = sl - le * Cc;
    int e = chunk0 + le;
    int cnt = counts[e];
    ushort_t* dst = xg + (size_t)sl * Dd + lane * 8;
    uint4 o;
    if (c < cnt) {
        int src = srcOf[e * Cc + c];
        const float4* xr = (const float4*)(x + (size_t)src * Dd + lane * 8);
        float4 v0 = xr[0], v1 = xr[1];
        o.x = (unsigned)f2bf(v0.x) | ((unsigned)f2bf(v0.y) << 16);
        o.y = (unsigned)f2bf(v0.z) | ((unsigned)f2bf(v0.w) << 16);
        o.z = (unsigned)f2bf(v1.x) | ((unsigned)f2bf(v1.y) << 16);
        o.w = (unsigned)f2bf(v1.z) | ((unsigned)f2bf(v1.w) << 16);
    } else {
        o = make_uint4(0, 0, 0, 0);
    }
    *(uint4*)dst = o;
}

// ---------------------------------------------------------------------------
// MFMA GEMM common structure (m97-style, verified pattern):
// 128x128 tile, BK=32, 4 waves, each wave 64x64 via 4x4 16x16x32_bf16 frags.
// LDS tiles laid out [kslot(4)][row(128)][8 bf16] -> linear global_load_lds,
// ds_read_b128 frag loads with 2-way max bank aliasing (free).
// A: [M][K] K-contig rows. B^T: [N][K] K-contig rows.
// ---------------------------------------------------------------------------

// Kernel 7: h = gelu(xg @ w1t^T + b1)  (per expert; M=Cc, N=Ff, K=Dd)
__global__ __launch_bounds__(256) void moe_mfma_gemm1(
    const ushort_t* __restrict__ xg, const ushort_t* __restrict__ w1t,
    const float* __restrict__ b1, int chunk0, ushort_t* __restrict__ hbuf) {
    int le = blockIdx.z, e = chunk0 + le;
    const ushort_t* A = xg + (size_t)le * Cc * Dd;
    const ushort_t* Bt = w1t + (size_t)e * Ff * Dd;
    const float* bias = b1 + (size_t)e * Ff;
    ushort_t* h = hbuf + (size_t)le * Cc * Ff;

    __shared__ short Al[4 * 128 * 8];   // 8 KB
    __shared__ short Bl[4 * 128 * 8];   // 8 KB

    int tid = threadIdx.x;
    int lane = tid & 63, wave = tid >> 6;
    int wr = wave >> 1, wc = wave & 1;
    int m0 = blockIdx.y * 128;
    int n0 = blockIdx.x * 128;
    int kslot = lane >> 4, lr = lane & 15;
    int aoff = (kslot * 128 + wr * 64 + lr) * 8;
    int boff = (kslot * 128 + wc * 64 + lr) * 8;
    int wbase = (tid & 192) * 8;        // wave-uniform LDS chunk base (elems)

    f32x4 acc[4][4] = {};

    for (int k0 = 0; k0 < Dd; k0 += 32) {
#pragma unroll
        for (int p = 0; p < 2; ++p) {
            int id = p * 256 + tid;
            int ks = id >> 7, row = id & 127;
            gload_lds16(A + (size_t)(m0 + row) * Dd + k0 + ks * 8,
                        &Al[p * 2048 + wbase]);
            gload_lds16(Bt + (size_t)(n0 + row) * Dd + k0 + ks * 8,
                        &Bl[p * 2048 + wbase]);
        }
        __syncthreads();
        bf16x8 a[4], b[4];
#pragma unroll
        for (int m = 0; m < 4; ++m) a[m] = *(const bf16x8*)&Al[aoff + m * 128];
#pragma unroll
        for (int n = 0; n < 4; ++n) b[n] = *(const bf16x8*)&Bl[boff + n * 128];
#pragma unroll
        for (int m = 0; m < 4; ++m)
#pragma unroll
            for (int n = 0; n < 4; ++n)
                acc[m][n] = __builtin_amdgcn_mfma_f32_16x16x32_bf16(
                    a[m], b[n], acc[m][n], 0, 0, 0);
        __syncthreads();
    }

    float bv[4];
#pragma unroll
    for (int n = 0; n < 4; ++n) bv[n] = bias[n0 + wc * 64 + n * 16 + lr];
#pragma unroll
    for (int m = 0; m < 4; ++m) {
#pragma unroll
        for (int r = 0; r < 4; ++r) {
            int row = m0 + wr * 64 + m * 16 + kslot * 4 + r;
            size_t base = (size_t)row * Ff + n0 + wc * 64 + lr;
#pragma unroll
            for (int n = 0; n < 4; ++n)
                h[base + n * 16] = f2bf(gelu_exact(acc[m][n][r] + bv[n]));
        }
    }
}

// Kernel 8: out[token] += w * (h @ w2t^T + b2)  (per expert; M=Cc, N=Dd, K=Ff)
__global__ __launch_bounds__(256) void moe_mfma_gemm2(
    const ushort_t* __restrict__ hbuf, const ushort_t* __restrict__ w2t,
    const float* __restrict__ b2, const int* __restrict__ srcOf,
    const float* __restrict__ wSlot, const int* __restrict__ counts,
    int chunk0, float* __restrict__ out) {
    int le = blockIdx.z, e = chunk0 + le;
    const ushort_t* A = hbuf + (size_t)le * Cc * Ff;
    const ushort_t* Bt = w2t + (size_t)e * Dd * Ff;
    const float* bias = b2 + (size_t)e * Dd;
    const int* srcE = srcOf + (size_t)e * Cc;
    const float* wE = wSlot + (size_t)e * Cc;
    int count = counts[e];

    __shared__ short Al[4 * 128 * 8];
    __shared__ short Bl[4 * 128 * 8];

    int tid = threadIdx.x;
    int lane = tid & 63, wave = tid >> 6;
    int wr = wave >> 1, wc = wave & 1;
    int m0 = blockIdx.y * 128;
    int n0 = blockIdx.x * 128;
    int kslot = lane >> 4, lr = lane & 15;
    int aoff = (kslot * 128 + wr * 64 + lr) * 8;
    int boff = (kslot * 128 + wc * 64 + lr) * 8;
    int wbase = (tid & 192) * 8;

    f32x4 acc[4][4] = {};

    for (int k0 = 0; k0 < Ff; k0 += 32) {
#pragma unroll
        for (int p = 0; p < 2; ++p) {
            int id = p * 256 + tid;
            int ks = id >> 7, row = id & 127;
            gload_lds16(A + (size_t)(m0 + row) * Ff + k0 + ks * 8,
                        &Al[p * 2048 + wbase]);
            gload_lds16(Bt + (size_t)(n0 + row) * Ff + k0 + ks * 8,
                        &Bl[p * 2048 + wbase]);
        }
        __syncthreads();
        bf16x8 a[4], b[4];
#pragma unroll
        for (int m = 0; m < 4; ++m) a[m] = *(const bf16x8*)&Al[aoff + m * 128];
#pragma unroll
        for (int n = 0; n < 4; ++n) b[n] = *(const bf16x8*)&Bl[boff + n * 128];
#pragma unroll
        for (int m = 0; m < 4; ++m)
#pragma unroll
            for (int n = 0; n < 4; ++n)
                acc[m][n] = __builtin_amdgcn_mfma_f32_16x16x32_bf16(
                    a[m], b[n], acc[m][n], 0, 0, 0);
        __syncthreads();
    }

    float bv[4];
#pragma unroll
    for (int n = 0; n < 4; ++n) bv[n] = bias[n0 + wc * 64 + n * 16 + lr];
#pragma unroll
    for (int m = 0; m < 4; ++m) {
#pragma unroll
        for (int r = 0; r < 4; ++r) {
            int row = m0 + wr * 64 + m * 16 + kslot * 4 + r;
            if (row < count) {
                int token = srcE[row];
                float wgt = wE[row];
                float* op = out + (size_t)token * Dd + n0 + wc * 64 + lr;
#pragma unroll
                for (int n = 0; n < 4; ++n)
                    atomicAdd(&op[n * 16], wgt * (acc[m][n][r] + bv[n]));
            }
        }
    }
}

// ---------------------------------------------------------------------------
extern "C" void kernel_launch(void* const* d_in, const int* in_sizes, int n_in,
                              void* d_out, int out_size, void* d_ws, size_t ws_size,
                              hipStream_t stream) {
    const float* x      = (const float*)d_in[0];
    const float* gate_w = (const float*)d_in[1];
    const float* w1     = (const float*)d_in[2];
    const float* b1     = (const float*)d_in[3];
    const float* w2     = (const float*)d_in[4];
    const float* b2     = (const float*)d_in[5];
    float* out = (float*)d_out;

    char* p = (char*)d_ws;
    int*      flat_e       = (int*)p;       p += (size_t)NK * 4;
    float*    wArr         = (float*)p;     p += (size_t)NK * 4;
    int*      blockCounts  = (int*)p;       p += 256 * Ee * 4;
    int*      blockOffsets = (int*)p;       p += 256 * Ee * 4;
    int*      counts       = (int*)p;       p += 64 * 4;
    int*      srcOf        = (int*)p;       p += (size_t)Ee * Cc * 4;
    float*    wSlot        = (float*)p;     p += (size_t)Ee * Cc * 4;
    p = (char*)(((size_t)p + 255) & ~(size_t)255);
    ushort_t* w1t          = (ushort_t*)p;  p += (size_t)Ee * Dd * Ff * 2;
    ushort_t* w2t          = (ushort_t*)p;  p += (size_t)Ee * Ff * Dd * 2;
    size_t fixedEnd = (size_t)(p - (char*)d_ws);
    size_t avail = (ws_size > fixedEnd) ? ws_size - fixedEnd : 0;

    // per-expert chunk buffers: xg (Cc x Dd bf16) + h (Cc x Ff bf16)
    size_t perE = (size_t)Cc * Dd * 2 + (size_t)Cc * Ff * 2;
    int P = Ee;
    while (P > 1 && (size_t)P * perE > avail) P >>= 1;
    ushort_t* xg = (ushort_t*)((char*)d_ws + fixedEnd);
    ushort_t* hbuf = xg + (size_t)P * Cc * Dd;

    moe_gate_kernel<<<Nn / 4, 256, 0, stream>>>(x, gate_w, flat_e, wArr);
    moe_hist_kernel<<<NK / 256, 256, 0, stream>>>(flat_e, blockCounts);
    moe_scan_kernel<<<1, 64, 0, stream>>>(blockCounts, blockOffsets, counts);
    moe_scatter_kernel<<<NK / 256, 256, 0, stream>>>(flat_e, wArr, blockOffsets,
                                                     srcOf, wSlot);
    // weights to bf16 B^T form
    moe_transpose_kernel<<<dim3(Ff / 32, Dd / 32, Ee), 256, 0, stream>>>(
        w1, w1t, Dd, Ff);
    moe_transpose_kernel<<<dim3(Dd / 32, Ff / 32, Ee), 256, 0, stream>>>(
        w2, w2t, Ff, Dd);
    hipMemsetAsync(d_out, 0, (size_t)Nn * Dd * sizeof(float), stream);

    for (int c0 = 0; c0 < Ee; c0 += P) {
        moe_gather_kernel<<<P * Cc / 4, 256, 0, stream>>>(x, srcOf, counts, c0, xg);
        moe_mfma_gemm1<<<dim3(Ff / 128, Cc / 128, P), 256, 0, stream>>>(
            xg, w1t, b1, c0, hbuf);
        moe_mfma_gemm2<<<dim3(Dd / 128, Cc / 128, P), 256, 0, stream>>>(
            hbuf, w2t, b2, srcOf, wSlot, counts, c0, out);
    }
}